// Round 3
// baseline (1128.141 us; speedup 1.0000x reference)
//
#include <hip/hip_runtime.h>

#define DD 32
#define NEG_SLOPE 0.01f
#define BN_EPS 1e-5f

// ---------------------------------------------------------------------------
__global__ void zero_kernel(float* p, int n) {
    int i = blockIdx.x * blockDim.x + threadIdx.x;
    if (i < n) p[i] = 0.0f;
}

// ---------------------------------------------------------------------------
// one thread per (edge, col): out[dst[e]][c] += ew[e] * x[src[e]][c]
__global__ void prop_kernel(const float* x, const int* src, const int* dst,
                            const float* ew, float* out, int E) {
    int t = blockIdx.x * blockDim.x + threadIdx.x;
    int e = t >> 5;
    if (e >= E) return;
    int c = t & 31;
    float v = ew[e] * x[src[e] * DD + c];
    atomicAdd(&out[dst[e] * DD + c], v);
}

// ---------------------------------------------------------------------------
// out[n][c] = bias[c] + sum_d x0[n][d]*W[0][d][c] + x1[n][d]*W[1][d][c]
//                     + x2[n][d]*W[2][d][c]
// W is [3][32][32] row-major. out may alias x0/x1/x2: row n is read only by
// the 32 lanes that write row n; all loads precede the store in the wave's
// single instruction stream, so the store cannot clobber a pending read.
__global__ void combine_kernel(const float* x0, const float* x1, const float* x2,
                               const float* W, const float* bias,
                               float* out, int N) {
    int t = blockIdx.x * blockDim.x + threadIdx.x;
    int n = t >> 5;
    if (n >= N) return;
    int c = t & 31;
    const float* r0 = x0 + n * DD;
    const float* r1 = x1 + n * DD;
    const float* r2 = x2 + n * DD;
    float acc = bias[c];
    for (int d = 0; d < DD; ++d) {
        acc += r0[d] * W[d * DD + c];
        acc += r1[d] * W[DD * DD + d * DD + c];
        acc += r2[d] * W[2 * DD * DD + d * DD + c];
    }
    out[t] = acc;   // t == n*DD + c
}

// ---------------------------------------------------------------------------
// deterministic per-column stats: block c computes sum and sumsq of column c.
// No atomics, no init required (absolute writes).
__global__ void stats_kernel(const float* x, float* stats, int N) {
    int c = blockIdx.x;            // 0..31
    int tid = threadIdx.x;         // 0..1023
    float s = 0.f, ss = 0.f;
    for (int r = tid; r < N; r += 1024) {
        float v = x[r * DD + c];
        s += v;
        ss += v * v;
    }
    __shared__ float shs[1024];
    __shared__ float shq[1024];
    shs[tid] = s;
    shq[tid] = ss;
    __syncthreads();
    for (int off = 512; off > 0; off >>= 1) {
        if (tid < off) { shs[tid] += shs[tid + off]; shq[tid] += shq[tid + off]; }
        __syncthreads();
    }
    if (tid == 0) { stats[c] = shs[0]; stats[DD + c] = shq[0]; }
}

// ---------------------------------------------------------------------------
// batchnorm (training stats, biased variance) + leaky relu
__global__ void bnrelu_kernel(const float* x, const float* stats,
                              const float* gamma, const float* beta,
                              float* out, int total, float invN) {
    int i = blockIdx.x * blockDim.x + threadIdx.x;
    if (i >= total) return;
    int c = i & 31;
    float m   = stats[c] * invN;
    float msq = stats[DD + c] * invN;
    float var = msq - m * m;
    float inv = 1.0f / sqrtf(var + BN_EPS);
    float v = (x[i] - m) * inv * gamma[c] + beta[c];
    out[i] = v >= 0.f ? v : NEG_SLOPE * v;
}

// ---------------------------------------------------------------------------
extern "C" void kernel_launch(void* const* d_in, const int* in_sizes, int n_in,
                              void* d_out, int out_size, void* d_ws, size_t ws_size,
                              hipStream_t stream) {
    const float* y   = (const float*)d_in[0];
    const int*   ei  = (const int*)d_in[1];
    const float* ew  = (const float*)d_in[2];
    const float* W1  = (const float*)d_in[3];
    const float* b1  = (const float*)d_in[4];
    const float* g1  = (const float*)d_in[5];
    const float* be1 = (const float*)d_in[6];
    const float* W2  = (const float*)d_in[7];
    const float* b2  = (const float*)d_in[8];
    const float* g2  = (const float*)d_in[9];
    const float* be2 = (const float*)d_in[10];
    float* out = (float*)d_out;

    const int N = in_sizes[0] / DD;     // 100000
    const int E = in_sizes[2];          // 1600000
    const int total = N * DD;           // 3,200,000

    const int* src = ei;                // edge_index[0] = first E ints
    const int* dst = ei + E;            // edge_index[1] = next E ints

    float* st = (float*)d_ws;           // 128 floats (layer1: 0..63, layer2: 64..127)
    float* h1 = st + 128;               // [N][32]
    float* h2 = h1 + total;             // [N][32]

    const int zgrid = (2 * total + 255) / 256;   // 25000
    const int pgrid = (E * DD + 255) / 256;      // 200000
    const int cgrid = (total + 255) / 256;       // 12500
    const float invN = 1.0f / (float)N;
    dim3 blk(256);

    // ---- layer 1 ----
    zero_kernel<<<zgrid, blk, 0, stream>>>(h1, 2 * total);
    prop_kernel<<<pgrid, blk, 0, stream>>>(y,  src, dst, ew, h1, E);
    prop_kernel<<<pgrid, blk, 0, stream>>>(h1, src, dst, ew, h2, E);
    combine_kernel<<<cgrid, blk, 0, stream>>>(y, h1, h2, W1, b1, out, N);
    stats_kernel<<<32, 1024, 0, stream>>>(out, st, N);
    bnrelu_kernel<<<cgrid, blk, 0, stream>>>(out, st, g1, be1, out, total, invN);

    // ---- layer 2 ----
    zero_kernel<<<zgrid, blk, 0, stream>>>(h1, 2 * total);
    prop_kernel<<<pgrid, blk, 0, stream>>>(out, src, dst, ew, h1, E);
    prop_kernel<<<pgrid, blk, 0, stream>>>(h1,  src, dst, ew, h2, E);
    combine_kernel<<<cgrid, blk, 0, stream>>>(out, h1, h2, W2, b2, out, N);
    stats_kernel<<<32, 1024, 0, stream>>>(out, st + 2 * DD, N);
    bnrelu_kernel<<<cgrid, blk, 0, stream>>>(out, st + 2 * DD, g2, be2, out, total, invN);
}

// Round 4
// 807.332 us; speedup vs baseline: 1.3974x; 1.3974x over previous
//
#include <hip/hip_runtime.h>

#define DD 32
#define NEG_SLOPE 0.01f
#define BN_EPS 1e-5f
#define SB 256          // stats partial blocks

// ======================= shared post-prop kernels (proven) =================

__global__ void zero_kernel(float* p, int n) {
    int i = blockIdx.x * blockDim.x + threadIdx.x;
    if (i < n) p[i] = 0.0f;
}

// out[n][c] = bias[c] + sum_d x0[n][d]*W[0][d][c] + x1*W[1] + x2*W[2]
// out may alias x0 (in-place layer 2): loads of row n all precede the store.
__global__ void combine_kernel(const float* x0, const float* x1, const float* x2,
                               const float* W, const float* bias,
                               float* out, int N) {
    int t = blockIdx.x * blockDim.x + threadIdx.x;
    int n = t >> 5;
    if (n >= N) return;
    int c = t & 31;
    const float* r0 = x0 + n * DD;
    const float* r1 = x1 + n * DD;
    const float* r2 = x2 + n * DD;
    float acc = bias[c];
    for (int d = 0; d < DD; ++d) {
        acc += r0[d] * W[d * DD + c];
        acc += r1[d] * W[DD * DD + d * DD + c];
        acc += r2[d] * W[2 * DD * DD + d * DD + c];
    }
    out[t] = acc;
}

// deterministic 2-stage stats: partials with contiguous coalesced loads
__global__ void stats_part_kernel(const float* x, float* part, int total) {
    int tid = threadIdx.x;
    int idx = blockIdx.x * 256 + tid;
    const int stride = SB * 256;             // multiple of 32
    float s = 0.f, ss = 0.f;
    for (int i = idx; i < total; i += stride) { float v = x[i]; s += v; ss += v * v; }
    __shared__ float sh[2][8][DD];
    sh[0][tid >> 5][tid & 31] = s;
    sh[1][tid >> 5][tid & 31] = ss;
    __syncthreads();
    if (tid < DD) {
        float ts = 0.f, tss = 0.f;
        for (int g = 0; g < 8; ++g) { ts += sh[0][g][tid]; tss += sh[1][g][tid]; }
        part[blockIdx.x * 64 + tid] = ts;
        part[blockIdx.x * 64 + DD + tid] = tss;
    }
}

__global__ void stats_final_kernel(const float* part, float* st) {
    int tid = threadIdx.x;                   // 64 threads
    if (tid < 64) {
        float a = 0.f;
        for (int b = 0; b < SB; ++b) a += part[b * 64 + tid];
        st[tid] = a;
    }
}

// fallback deterministic stats (round-3, proven)
__global__ void stats_kernel(const float* x, float* stats, int N) {
    int c = blockIdx.x;
    int tid = threadIdx.x;
    float s = 0.f, ss = 0.f;
    for (int r = tid; r < N; r += 1024) {
        float v = x[r * DD + c];
        s += v; ss += v * v;
    }
    __shared__ float shs[1024];
    __shared__ float shq[1024];
    shs[tid] = s; shq[tid] = ss;
    __syncthreads();
    for (int off = 512; off > 0; off >>= 1) {
        if (tid < off) { shs[tid] += shs[tid + off]; shq[tid] += shq[tid + off]; }
        __syncthreads();
    }
    if (tid == 0) { stats[c] = shs[0]; stats[DD + c] = shq[0]; }
}

__global__ void bnrelu_kernel(const float* x, const float* stats,
                              const float* gamma, const float* beta,
                              float* out, int total, float invN) {
    int i = blockIdx.x * blockDim.x + threadIdx.x;
    if (i >= total) return;
    int c = i & 31;
    float m   = stats[c] * invN;
    float msq = stats[DD + c] * invN;
    float var = msq - m * m;
    float inv = 1.0f / sqrtf(var + BN_EPS);
    float v = (x[i] - m) * inv * gamma[c] + beta[c];
    out[i] = v >= 0.f ? v : NEG_SLOPE * v;
}

// ======================= CSR build =========================================

__global__ void zero_int_kernel(int* p, int n) {
    int i = blockIdx.x * blockDim.x + threadIdx.x;
    if (i < n) p[i] = 0;
}

__global__ void hist_kernel(const int* dst, int* deg, int E) {
    int e = blockIdx.x * blockDim.x + threadIdx.x;
    if (e < E) atomicAdd(&deg[dst[e]], 1);
}

// per-block exclusive scan (Hillis-Steele in LDS), pre-offset result + block sums
__global__ void scan_block_kernel(const int* deg, int* pre, int* bsum, int N) {
    __shared__ int sh[1024];
    int tid = threadIdx.x;
    int i = blockIdx.x * 1024 + tid;
    int v = (i < N) ? deg[i] : 0;
    sh[tid] = v;
    __syncthreads();
    for (int off = 1; off < 1024; off <<= 1) {
        int t = (tid >= off) ? sh[tid - off] : 0;
        __syncthreads();
        sh[tid] += t;
        __syncthreads();
    }
    if (i < N) pre[i] = sh[tid] - v;         // exclusive
    if (tid == 1023) bsum[blockIdx.x] = sh[1023];
}

__global__ void scan_sums_kernel(const int* bsum, int* boff, int nb) {
    if (threadIdx.x == 0) {
        int run = 0;
        for (int i = 0; i < nb; ++i) { boff[i] = run; run += bsum[i]; }
    }
}

__global__ void add_off_kernel(int* rowptr, const int* boff, int N, int E) {
    int i = blockIdx.x * blockDim.x + threadIdx.x;
    if (i < N) rowptr[i] += boff[i >> 10];
    if (i == 0) rowptr[N] = E;
}

__global__ void copy_int_kernel(const int* a, int* b, int n) {
    int i = blockIdx.x * blockDim.x + threadIdx.x;
    if (i < n) b[i] = a[i];
}

__global__ void fill_kernel(const int* src, const int* dst, const float* ew,
                            int* cursor, int* psrc, float* pw, int E) {
    int e = blockIdx.x * blockDim.x + threadIdx.x;
    if (e >= E) return;
    int p = atomicAdd(&cursor[dst[e]], 1);
    psrc[p] = src[e];
    pw[p] = ew[e];
}

// ======================= atomic-free gather propagation ====================

__global__ void gather_prop_kernel(const float* x, const int* rowptr,
                                   const int* psrc, const float* pw,
                                   float* out, int N) {
    int t = blockIdx.x * blockDim.x + threadIdx.x;
    int n = t >> 5;
    if (n >= N) return;
    int c = t & 31;
    int b = rowptr[n], e = rowptr[n + 1];
    float acc = 0.f;
    for (int j = b; j < e; ++j)
        acc += pw[j] * x[psrc[j] * DD + c];
    out[n * DD + c] = acc;
}

// ======================= fallback scatter (round-3, proven) ================

__global__ void prop_kernel(const float* x, const int* src, const int* dst,
                            const float* ew, float* out, int E) {
    int t = blockIdx.x * blockDim.x + threadIdx.x;
    int e = t >> 5;
    if (e >= E) return;
    int c = t & 31;
    float v = ew[e] * x[src[e] * DD + c];
    atomicAdd(&out[dst[e] * DD + c], v);
}

// ===========================================================================

extern "C" void kernel_launch(void* const* d_in, const int* in_sizes, int n_in,
                              void* d_out, int out_size, void* d_ws, size_t ws_size,
                              hipStream_t stream) {
    const float* y   = (const float*)d_in[0];
    const int*   ei  = (const int*)d_in[1];
    const float* ew  = (const float*)d_in[2];
    const float* W1  = (const float*)d_in[3];
    const float* b1  = (const float*)d_in[4];
    const float* g1  = (const float*)d_in[5];
    const float* be1 = (const float*)d_in[6];
    const float* W2  = (const float*)d_in[7];
    const float* b2  = (const float*)d_in[8];
    const float* g2  = (const float*)d_in[9];
    const float* be2 = (const float*)d_in[10];
    float* out = (float*)d_out;

    const int N = in_sizes[0] / DD;     // 100000
    const int E = in_sizes[2];          // 1600000
    const int total = N * DD;

    const int* src = ei;
    const int* dst = ei + E;

    // persistent ws layout
    float* st       = (float*)d_ws;              // 128 f
    float* h1       = st + 128;                  // total f
    float* h2       = h1 + total;                // total f
    int*   rowptr   = (int*)(h2 + total);        // N+1 i
    int*   perm_src = rowptr + (N + 1);          // E i
    float* perm_w   = (float*)(perm_src + E);    // E f
    float* part     = perm_w + E;                // SB*64 f

    const size_t need = (size_t)(128 + 2 * (size_t)total + (N + 1) + 2 * (size_t)E + SB * 64) * 4;
    const bool use_csr = ws_size >= need;

    // scratch temporaries aliased into h1/h2 (only used before props run)
    int* cursor = (int*)h1;                      // N i
    int* bsum   = (int*)h1 + N;                  // ≤128 i
    int* boff   = bsum + 128;                    // ≤128 i
    int* deg    = (int*)h2;                      // N i

    const int NB = (N + 1023) / 1024;            // 98
    const float invN = 1.0f / (float)N;
    dim3 blk(256);
    const int ngrid = (N + 255) / 256;
    const int egrid = (E + 255) / 256;
    const int cgrid = (total + 255) / 256;       // node*col grid
    const int zgrid = (2 * total + 255) / 256;
    const int pgrid = (E * DD + 255) / 256;

    if (use_csr) {
        // ---- build CSR by destination (graph shared by all 4 props) ----
        zero_int_kernel<<<ngrid, blk, 0, stream>>>(deg, N);
        hist_kernel<<<egrid, blk, 0, stream>>>(dst, deg, E);
        scan_block_kernel<<<NB, 1024, 0, stream>>>(deg, rowptr, bsum, N);
        scan_sums_kernel<<<1, 64, 0, stream>>>(bsum, boff, NB);
        add_off_kernel<<<ngrid, blk, 0, stream>>>(rowptr, boff, N, E);
        copy_int_kernel<<<ngrid, blk, 0, stream>>>(rowptr, cursor, N);
        fill_kernel<<<egrid, blk, 0, stream>>>(src, dst, ew, cursor, perm_src, perm_w, E);

        // ---- layer 1 ----
        gather_prop_kernel<<<cgrid, blk, 0, stream>>>(y,  rowptr, perm_src, perm_w, h1, N);
        gather_prop_kernel<<<cgrid, blk, 0, stream>>>(h1, rowptr, perm_src, perm_w, h2, N);
        combine_kernel<<<cgrid, blk, 0, stream>>>(y, h1, h2, W1, b1, out, N);
        stats_part_kernel<<<SB, blk, 0, stream>>>(out, part, total);
        stats_final_kernel<<<1, 64, 0, stream>>>(part, st);
        bnrelu_kernel<<<cgrid, blk, 0, stream>>>(out, st, g1, be1, out, total, invN);

        // ---- layer 2 ----
        gather_prop_kernel<<<cgrid, blk, 0, stream>>>(out, rowptr, perm_src, perm_w, h1, N);
        gather_prop_kernel<<<cgrid, blk, 0, stream>>>(h1,  rowptr, perm_src, perm_w, h2, N);
        combine_kernel<<<cgrid, blk, 0, stream>>>(out, h1, h2, W2, b2, out, N);
        stats_part_kernel<<<SB, blk, 0, stream>>>(out, part, total);
        stats_final_kernel<<<1, 64, 0, stream>>>(part, st + 64);
        bnrelu_kernel<<<cgrid, blk, 0, stream>>>(out, st + 64, g2, be2, out, total, invN);
    } else {
        // ---- fallback: exact round-3 path ----
        zero_kernel<<<zgrid, blk, 0, stream>>>(h1, 2 * total);
        prop_kernel<<<pgrid, blk, 0, stream>>>(y,  src, dst, ew, h1, E);
        prop_kernel<<<pgrid, blk, 0, stream>>>(h1, src, dst, ew, h2, E);
        combine_kernel<<<cgrid, blk, 0, stream>>>(y, h1, h2, W1, b1, out, N);
        stats_kernel<<<32, 1024, 0, stream>>>(out, st, N);
        bnrelu_kernel<<<cgrid, blk, 0, stream>>>(out, st, g1, be1, out, total, invN);

        zero_kernel<<<zgrid, blk, 0, stream>>>(h1, 2 * total);
        prop_kernel<<<pgrid, blk, 0, stream>>>(out, src, dst, ew, h1, E);
        prop_kernel<<<pgrid, blk, 0, stream>>>(h1,  src, dst, ew, h2, E);
        combine_kernel<<<cgrid, blk, 0, stream>>>(out, h1, h2, W2, b2, out, N);
        stats_kernel<<<32, 1024, 0, stream>>>(out, st + 2 * DD, N);
        bnrelu_kernel<<<cgrid, blk, 0, stream>>>(out, st + 2 * DD, g2, be2, out, total, invN);
    }
}